// Round 4
// baseline (297.090 us; speedup 1.0000x reference)
//
#include <hip/hip_runtime.h>
#include <hip/hip_fp16.h>
#include <math.h>

#define EPS_Q 1e-8f

struct F3 { float x, y, z; };
struct Q4 { F3 v; float w; };

typedef float    fvec4 __attribute__((ext_vector_type(4)));
typedef unsigned uvec4 __attribute__((ext_vector_type(4)));
typedef int      ivec2 __attribute__((ext_vector_type(2)));
typedef int      ivec4 __attribute__((ext_vector_type(4)));

__device__ __forceinline__ F3 add3(F3 a, F3 b){ return {a.x+b.x, a.y+b.y, a.z+b.z}; }
__device__ __forceinline__ F3 sub3(F3 a, F3 b){ return {a.x-b.x, a.y-b.y, a.z-b.z}; }
__device__ __forceinline__ F3 scal3(float s, F3 a){ return {s*a.x, s*a.y, s*a.z}; }
__device__ __forceinline__ float dot3(F3 a, F3 b){ return a.x*b.x + a.y*b.y + a.z*b.z; }
__device__ __forceinline__ F3 cross3(F3 a, F3 b){
    return { a.y*b.z - a.z*b.y, a.z*b.x - a.x*b.z, a.x*b.y - a.y*b.x };
}

__device__ __forceinline__ Q4 qmul(Q4 q, Q4 r){
    Q4 o;
    o.w = q.w*r.w - dot3(q.v, r.v);
    o.v = add3(add3(scal3(q.w, r.v), scal3(r.w, q.v)), cross3(q.v, r.v));
    return o;
}
__device__ __forceinline__ Q4 qconj(Q4 q){ return { {-q.v.x, -q.v.y, -q.v.z}, q.w }; }
__device__ __forceinline__ F3 qrot(Q4 q, F3 v){
    F3 t = scal3(2.0f, cross3(q.v, v));
    return add3(add3(v, scal3(q.w, t)), cross3(q.v, t));
}
// matches reference so3_log branch semantics exactly
__device__ __forceinline__ F3 so3_log(Q4 q){
    float n = sqrtf(dot3(q.v, q.v));
    float theta = 2.0f * atan2f(n, q.w);
    float k;
    if (n > EPS_Q) k = theta / n;
    else           k = 2.0f / ((fabsf(q.w) > EPS_Q) ? q.w : 1.0f);
    return scal3(k, q.v);
}

// non-temporal helpers for single-use streams
__device__ __forceinline__ float ntl (const float* p){ return __builtin_nontemporal_load(p); }
__device__ __forceinline__ void  nts (float* p, float v){ __builtin_nontemporal_store(v, p); }

__device__ __forceinline__ unsigned pack2h(float a, float b){
    __half2 h = __floats2half2_rn(a, b);
    unsigned u; __builtin_memcpy(&u, &h, 4);
    return u;
}
__device__ __forceinline__ float2 unp2h(unsigned u){
    __half2 h; __builtin_memcpy(&h, &u, 4);
    return __half22float2(h);
}

// ---------------------------------------------------------------------------
// pack kernel: nodes (28B rows) -> nodes16 (16B fp16 rows), LDS-staged so the
// global reads are perfectly coalesced dword streams.  ~44 MB total.
// ---------------------------------------------------------------------------
__global__ __launch_bounds__(256)
void pack_kernel(const float* __restrict__ nodes, uvec4* __restrict__ nodes16, int N)
{
    __shared__ float s[7*256];
    const int tid  = threadIdx.x;
    const int base = blockIdx.x * 256;
    const int nrows = min(256, N - base);
    const int ndw   = nrows * 7;

    #pragma unroll
    for (int k = 0; k < 7; ++k) {
        int idx = k*256 + tid;
        if (idx < ndw) s[idx] = ntl(nodes + (size_t)base*7 + idx);
    }
    __syncthreads();

    if (tid < nrows) {
        const float* r = s + 7*tid;   // stride 7 is coprime with 32 banks: conflict-free
        uvec4 row = { pack2h(r[0], r[1]), pack2h(r[2], 0.0f),
                      pack2h(r[3], r[4]), pack2h(r[5], r[6]) };
        __builtin_nontemporal_store(row, nodes16 + base + tid);
    }
}

// ---------------------------------------------------------------------------
// edge residual math (pose already loaded)
// ---------------------------------------------------------------------------
__device__ __forceinline__ void edge_math(F3 t1, Q4 q1, F3 t2, Q4 q2,
                                          F3 tp, Q4 qp, float* __restrict__ o)
{
    Q4 qi1 = qconj(q1);
    F3 ti1 = scal3(-1.0f, qrot(qi1, t1));
    Q4 qa  = qmul(qi1, q2);
    F3 ta  = add3(ti1, qrot(qi1, t2));

    Q4 qip = qconj(qp);
    F3 tip = scal3(-1.0f, qrot(qip, tp));
    Q4 qe  = qmul(qip, qa);
    F3 te  = add3(tip, qrot(qip, ta));

    F3 phi = so3_log(qe);
    float theta2 = dot3(phi, phi);
    float theta  = sqrtf(theta2);
    float coef;
    if (theta < 1e-4f) {
        coef = 1.0f / 12.0f;
    } else {
        float s, c;
        sincosf(theta, &s, &c);
        coef = 1.0f / theta2 - (1.0f + c) / (2.0f * theta * s);
    }
    F3 pxt = cross3(phi, te);
    F3 tau = add3(sub3(te, scal3(0.5f, pxt)), scal3(coef, cross3(phi, pxt)));

    nts(o,   tau.x); nts(o+1, tau.y); nts(o+2, tau.z);
    nts(o+3, phi.x); nts(o+4, phi.y); nts(o+5, phi.z);
}

__device__ __forceinline__ void unpack_rows(uvec4 r1, uvec4 r2,
                                            F3& t1, Q4& q1, F3& t2, Q4& q2)
{
    float2 a0 = unp2h(r1.x), a1 = unp2h(r1.y), a2 = unp2h(r1.z), a3 = unp2h(r1.w);
    float2 b0 = unp2h(r2.x), b1 = unp2h(r2.y), b2 = unp2h(r2.z), b3 = unp2h(r2.w);
    t1 = {a0.x, a0.y, a1.x};  q1 = {{a2.x, a2.y, a3.x}, a3.y};
    t2 = {b0.x, b0.y, b1.x};  q2 = {{b2.x, b2.y, b3.x}, b3.y};
}

// 2 edges/thread: doubles per-wave gather MLP (probe: is 3.9 TB/s an
// outstanding-miss limit or a hard mixed-traffic ceiling?)
__global__ __launch_bounds__(256)
void edge_kernel2(const int*   __restrict__ edges,
                  const uvec4* __restrict__ nodes16,
                  const float* __restrict__ poses,
                  float*       __restrict__ out,
                  int E)
{
    const int t  = blockIdx.x * 256 + threadIdx.x;
    const int e0 = 2*t, e1 = 2*t + 1;
    if (e0 >= E) return;
    const bool has1 = (e1 < E);

    // one 16B load covers both edges' indices
    ivec4 ij;
    if (has1) {
        ij = __builtin_nontemporal_load(reinterpret_cast<const ivec4*>(edges) + t);
    } else {
        ivec2 a = __builtin_nontemporal_load(reinterpret_cast<const ivec2*>(edges) + e0);
        ij = {a.x, a.y, a.x, a.y};
    }

    // issue ALL gathers first — they are the long-latency path
    uvec4 r1a = nodes16[ij.x];
    uvec4 r2a = nodes16[ij.y];
    uvec4 r1b = nodes16[ij.z];
    uvec4 r2b = nodes16[ij.w];

    // pose rows for e0,e1 are 14 consecutive dwords
    const float* p = poses + 7*(size_t)e0;
    float pv[14];
    #pragma unroll
    for (int k = 0; k < 7; ++k) pv[k] = ntl(p + k);
    if (has1) {
        #pragma unroll
        for (int k = 7; k < 14; ++k) pv[k] = ntl(p + k);
    }

    F3 t1, t2; Q4 q1, q2;
    unpack_rows(r1a, r2a, t1, q1, t2, q2);
    edge_math(t1, q1, t2, q2,
              F3{pv[0], pv[1], pv[2]}, Q4{{pv[3], pv[4], pv[5]}, pv[6]},
              out + 6*(size_t)e0);

    if (has1) {
        unpack_rows(r1b, r2b, t1, q1, t2, q2);
        edge_math(t1, q1, t2, q2,
                  F3{pv[7], pv[8], pv[9]}, Q4{{pv[10], pv[11], pv[12]}, pv[13]},
                  out + 6*(size_t)e1);
    }
}

// fallback (workspace too small): gather f32 rows directly, 1 edge/thread
__global__ __launch_bounds__(256)
void edge_kernel_direct(const int*   __restrict__ edges,
                        const float* __restrict__ nodes,
                        const float* __restrict__ poses,
                        float*       __restrict__ out,
                        int E)
{
    const int e = blockIdx.x * 256 + threadIdx.x;
    if (e >= E) return;

    ivec2 ij = __builtin_nontemporal_load(reinterpret_cast<const ivec2*>(edges) + e);
    const float* n1 = nodes + 7*(size_t)ij.x;
    const float* n2 = nodes + 7*(size_t)ij.y;
    const float* p  = poses + 7*(size_t)e;

    F3 t1 = {n1[0], n1[1], n1[2]};  Q4 q1 = {{n1[3], n1[4], n1[5]}, n1[6]};
    F3 t2 = {n2[0], n2[1], n2[2]};  Q4 q2 = {{n2[3], n2[4], n2[5]}, n2[6]};
    edge_math(t1, q1, t2, q2,
              F3{ntl(p+0), ntl(p+1), ntl(p+2)}, Q4{{ntl(p+3), ntl(p+4), ntl(p+5)}, ntl(p+6)},
              out + 6*(size_t)e);
}

// ---------------------------------------------------------------------------
// node-adjacency residuals: pure nt streaming (round-0 structure, which ran
// at the ~6.3 TB/s streaming ceiling; the fused pack version lost ~35%)
// ---------------------------------------------------------------------------
__global__ __launch_bounds__(256)
void node_kernel(const float* __restrict__ nodes,
                 const float* __restrict__ vels,
                 const float* __restrict__ imu_drots,
                 const float* __restrict__ imu_dtrans,
                 const float* __restrict__ imu_dvels,
                 const float* __restrict__ dts,
                 float*       __restrict__ out,
                 int M,
                 size_t off_adjvel, size_t off_imurot, size_t off_transvel)
{
    const int m = blockIdx.x * 256 + threadIdx.x;
    if (m >= M) return;

    const float* n0 = nodes + 7*(size_t)m;
    const float* n1 = nodes + 7*(size_t)(m+1);
    F3 t0 = {n0[0], n0[1], n0[2]};  Q4 q0 = {{n0[3], n0[4], n0[5]}, n0[6]};
    F3 t1 = {n1[0], n1[1], n1[2]};  Q4 q1 = {{n1[3], n1[4], n1[5]}, n1[6]};

    F3 v0 = {vels[3*(size_t)m],     vels[3*(size_t)m + 1], vels[3*(size_t)m + 2]};
    F3 v1 = {vels[3*(size_t)m + 3], vels[3*(size_t)m + 4], vels[3*(size_t)m + 5]};

    fvec4 drq = __builtin_nontemporal_load(reinterpret_cast<const fvec4*>(imu_drots) + m);
    Q4 dr = {{drq.x, drq.y, drq.z}, drq.w};

    F3 dvm = { ntl(imu_dvels + 3*(size_t)m),
               ntl(imu_dvels + 3*(size_t)m + 1),
               ntl(imu_dvels + 3*(size_t)m + 2) };
    F3 dtr = { ntl(imu_dtrans + 3*(size_t)m),
               ntl(imu_dtrans + 3*(size_t)m + 1),
               ntl(imu_dtrans + 3*(size_t)m + 2) };
    float dt = ntl(dts + m);

    F3 adjv = sub3(dvm, sub3(v1, v0));
    nts(out + off_adjvel + 3*(size_t)m,     0.1f * adjv.x);
    nts(out + off_adjvel + 3*(size_t)m + 1, 0.1f * adjv.y);
    nts(out + off_adjvel + 3*(size_t)m + 2, 0.1f * adjv.z);

    Q4 qre = qmul(qconj(dr), qmul(qconj(q0), q1));
    F3 rot = so3_log(qre);
    nts(out + off_imurot + 3*(size_t)m,     rot.x);
    nts(out + off_imurot + 3*(size_t)m + 1, rot.y);
    nts(out + off_imurot + 3*(size_t)m + 2, rot.z);

    F3 tv = sub3(sub3(t1, t0), add3(scal3(dt, v0), dtr));
    nts(out + off_transvel + 3*(size_t)m,     0.1f * tv.x);
    nts(out + off_transvel + 3*(size_t)m + 1, 0.1f * tv.y);
    nts(out + off_transvel + 3*(size_t)m + 2, 0.1f * tv.z);
}

extern "C" void kernel_launch(void* const* d_in, const int* in_sizes, int n_in,
                              void* d_out, int out_size, void* d_ws, size_t ws_size,
                              hipStream_t stream) {
    const int*   edges      = (const int*)  d_in[0];
    const float* nodes      = (const float*)d_in[1];
    const float* vels       = (const float*)d_in[2];
    const float* poses      = (const float*)d_in[3];
    const float* imu_drots  = (const float*)d_in[4];
    const float* imu_dtrans = (const float*)d_in[5];
    const float* imu_dvels  = (const float*)d_in[6];
    const float* dts        = (const float*)d_in[7];
    float* out = (float*)d_out;

    const int E = in_sizes[0] / 2;
    const int N = in_sizes[1] / 7;
    const int M = in_sizes[7];

    const size_t off_adjvel   = 6*(size_t)E;
    const size_t off_imurot   = off_adjvel + 3*(size_t)M;
    const size_t off_transvel = off_imurot + 3*(size_t)M;

    const int BLK = 256;
    uvec4* nodes16 = (uvec4*)d_ws;
    const bool can_pack = (d_ws != nullptr) && (ws_size >= (size_t)N * 16);

    if (can_pack) {
        pack_kernel<<<(N + BLK - 1)/BLK, BLK, 0, stream>>>(nodes, nodes16, N);
        edge_kernel2<<<(E + 2*BLK - 1)/(2*BLK), BLK, 0, stream>>>(edges, nodes16, poses, out, E);
    } else {
        edge_kernel_direct<<<(E + BLK - 1)/BLK, BLK, 0, stream>>>(edges, nodes, poses, out, E);
    }
    node_kernel<<<(M + BLK - 1)/BLK, BLK, 0, stream>>>(nodes, vels, imu_drots, imu_dtrans,
                                                       imu_dvels, dts, out, M,
                                                       off_adjvel, off_imurot, off_transvel);
}

// Round 5
// 258.165 us; speedup vs baseline: 1.1508x; 1.1508x over previous
//
#include <hip/hip_runtime.h>
#include <hip/hip_fp16.h>
#include <math.h>

#define EPS_Q 1e-8f

struct F3 { float x, y, z; };
struct Q4 { F3 v; float w; };

typedef float    fvec4 __attribute__((ext_vector_type(4)));
typedef unsigned uvec4 __attribute__((ext_vector_type(4)));
typedef int      ivec2 __attribute__((ext_vector_type(2)));

__device__ __forceinline__ F3 add3(F3 a, F3 b){ return {a.x+b.x, a.y+b.y, a.z+b.z}; }
__device__ __forceinline__ F3 sub3(F3 a, F3 b){ return {a.x-b.x, a.y-b.y, a.z-b.z}; }
__device__ __forceinline__ F3 scal3(float s, F3 a){ return {s*a.x, s*a.y, s*a.z}; }
__device__ __forceinline__ float dot3(F3 a, F3 b){ return a.x*b.x + a.y*b.y + a.z*b.z; }
__device__ __forceinline__ F3 cross3(F3 a, F3 b){
    return { a.y*b.z - a.z*b.y, a.z*b.x - a.x*b.z, a.x*b.y - a.y*b.x };
}

__device__ __forceinline__ Q4 qmul(Q4 q, Q4 r){
    Q4 o;
    o.w = q.w*r.w - dot3(q.v, r.v);
    o.v = add3(add3(scal3(q.w, r.v), scal3(r.w, q.v)), cross3(q.v, r.v));
    return o;
}
__device__ __forceinline__ Q4 qconj(Q4 q){ return { {-q.v.x, -q.v.y, -q.v.z}, q.w }; }
__device__ __forceinline__ F3 qrot(Q4 q, F3 v){
    F3 t = scal3(2.0f, cross3(q.v, v));
    return add3(add3(v, scal3(q.w, t)), cross3(q.v, t));
}
// matches reference so3_log branch semantics exactly
__device__ __forceinline__ F3 so3_log(Q4 q){
    float n = sqrtf(dot3(q.v, q.v));
    float theta = 2.0f * atan2f(n, q.w);
    float k;
    if (n > EPS_Q) k = theta / n;
    else           k = 2.0f / ((fabsf(q.w) > EPS_Q) ? q.w : 1.0f);
    return scal3(k, q.v);
}

// non-temporal helpers for single-use streams
__device__ __forceinline__ float ntl (const float* p){ return __builtin_nontemporal_load(p); }
__device__ __forceinline__ void  nts (float* p, float v){ __builtin_nontemporal_store(v, p); }

__device__ __forceinline__ unsigned pack2h(float a, float b){
    __half2 h = __floats2half2_rn(a, b);
    unsigned u; __builtin_memcpy(&u, &h, 4);
    return u;
}
__device__ __forceinline__ float2 unp2h(unsigned u){
    __half2 h; __builtin_memcpy(&h, &u, 4);
    return __half22float2(h);
}

// ---------------------------------------------------------------------------
// prep kernel (round-3 proven version): streams nodes once; packs 16B fp16
// rows for the edge gathers AND computes the node-adjacency residuals.
// ---------------------------------------------------------------------------
template<bool PACK>
__global__ __launch_bounds__(256)
void prep_kernel(const float* __restrict__ nodes,
                 const float* __restrict__ vels,
                 const float* __restrict__ imu_drots,
                 const float* __restrict__ imu_dtrans,
                 const float* __restrict__ imu_dvels,
                 const float* __restrict__ dts,
                 float*       __restrict__ out,
                 uvec4*       __restrict__ nodes16,
                 int N, int M,
                 size_t off_adjvel, size_t off_imurot, size_t off_transvel)
{
    const int m = blockIdx.x * 256 + threadIdx.x;
    if (m >= N) return;

    const float* n0 = nodes + 7*(size_t)m;
    F3 t0 = {n0[0], n0[1], n0[2]};  Q4 q0 = {{n0[3], n0[4], n0[5]}, n0[6]};

    if (PACK) {
        uvec4 row = { pack2h(t0.x, t0.y), pack2h(t0.z, 0.0f),
                      pack2h(q0.v.x, q0.v.y), pack2h(q0.v.z, q0.w) };
        nodes16[m] = row;   // normal store: stays L2/L3-resident for the edge phase
    }

    if (m >= M) return;

    const float* n1p = nodes + 7*(size_t)(m+1);
    F3 t1 = {n1p[0], n1p[1], n1p[2]};  Q4 q1 = {{n1p[3], n1p[4], n1p[5]}, n1p[6]};

    F3 v0 = {vels[3*(size_t)m],     vels[3*(size_t)m + 1], vels[3*(size_t)m + 2]};
    F3 v1 = {vels[3*(size_t)m + 3], vels[3*(size_t)m + 4], vels[3*(size_t)m + 5]};

    fvec4 drq = __builtin_nontemporal_load(reinterpret_cast<const fvec4*>(imu_drots) + m);
    Q4 dr = {{drq.x, drq.y, drq.z}, drq.w};

    F3 dvm = { ntl(imu_dvels + 3*(size_t)m),
               ntl(imu_dvels + 3*(size_t)m + 1),
               ntl(imu_dvels + 3*(size_t)m + 2) };
    F3 dtr = { ntl(imu_dtrans + 3*(size_t)m),
               ntl(imu_dtrans + 3*(size_t)m + 1),
               ntl(imu_dtrans + 3*(size_t)m + 2) };
    float dt = ntl(dts + m);

    F3 adjv = sub3(dvm, sub3(v1, v0));
    nts(out + off_adjvel + 3*(size_t)m,     0.1f * adjv.x);
    nts(out + off_adjvel + 3*(size_t)m + 1, 0.1f * adjv.y);
    nts(out + off_adjvel + 3*(size_t)m + 2, 0.1f * adjv.z);

    Q4 qre = qmul(qconj(dr), qmul(qconj(q0), q1));
    F3 rot = so3_log(qre);
    nts(out + off_imurot + 3*(size_t)m,     rot.x);
    nts(out + off_imurot + 3*(size_t)m + 1, rot.y);
    nts(out + off_imurot + 3*(size_t)m + 2, rot.z);

    F3 tv = sub3(sub3(t1, t0), add3(scal3(dt, v0), dtr));
    nts(out + off_transvel + 3*(size_t)m,     0.1f * tv.x);
    nts(out + off_transvel + 3*(size_t)m + 1, 0.1f * tv.y);
    nts(out + off_transvel + 3*(size_t)m + 2, 0.1f * tv.z);
}

// ---------------------------------------------------------------------------
// edge residual math
// ---------------------------------------------------------------------------
__device__ __forceinline__ void edge_math(F3 t1, Q4 q1, F3 t2, Q4 q2,
                                          F3 tp, Q4 qp, float res[6])
{
    Q4 qi1 = qconj(q1);
    F3 ti1 = scal3(-1.0f, qrot(qi1, t1));
    Q4 qa  = qmul(qi1, q2);
    F3 ta  = add3(ti1, qrot(qi1, t2));

    Q4 qip = qconj(qp);
    F3 tip = scal3(-1.0f, qrot(qip, tp));
    Q4 qe  = qmul(qip, qa);
    F3 te  = add3(tip, qrot(qip, ta));

    F3 phi = so3_log(qe);
    float theta2 = dot3(phi, phi);
    float theta  = sqrtf(theta2);
    float coef;
    if (theta < 1e-4f) {
        coef = 1.0f / 12.0f;
    } else {
        float s, c;
        sincosf(theta, &s, &c);
        coef = 1.0f / theta2 - (1.0f + c) / (2.0f * theta * s);
    }
    F3 pxt = cross3(phi, te);
    F3 tau = add3(sub3(te, scal3(0.5f, pxt)), scal3(coef, cross3(phi, pxt)));

    res[0] = tau.x; res[1] = tau.y; res[2] = tau.z;
    res[3] = phi.x; res[4] = phi.y; res[5] = phi.z;
}

// ---------------------------------------------------------------------------
// edge kernel v3: gathers unchanged (1 edge/thread, 2×dwordx4), but poses and
// out are staged through LDS so every global access is a fully-used 64B line:
//   poses: coalesced nt dwordx4 loads  (was 7 scalar loads over 28 part-lines)
//   out:   coalesced nt dwordx4 stores (was 6 scalar nt stores, partial lines)
// Probe: is the 3.9 TB/s edge-mix rate TCP/request-limited (this should lift
// it) or L2-fill-bound (this is a null)?
// ---------------------------------------------------------------------------
__global__ __launch_bounds__(256)
void edge_kernel3(const int*   __restrict__ edges,
                  const uvec4* __restrict__ nodes16,
                  const float* __restrict__ poses,
                  float*       __restrict__ out,
                  int E)
{
    __shared__ __attribute__((aligned(16))) float sp[7*256];  // staged poses
    __shared__ __attribute__((aligned(16))) float so[6*256];  // staged outputs

    const int tid   = threadIdx.x;
    const int b0    = blockIdx.x * 256;          // first edge of this block
    const int nrows = min(256, E - b0);
    const bool active = (tid < nrows);

    // 1) issue the long-latency gathers FIRST (overlap with pose staging)
    ivec2 ij = {0, 0};
    uvec4 r1 = {0,0,0,0}, r2 = {0,0,0,0};
    if (active) {
        ij = __builtin_nontemporal_load(reinterpret_cast<const ivec2*>(edges) + (b0 + tid));
        r1 = nodes16[ij.x];
        r2 = nodes16[ij.y];
    }

    // 2) stage this block's poses: nrows*7 dwords, coalesced dwordx4
    {
        const float* src = poses + 7*(size_t)b0;   // 28*b0 bytes: 16B-aligned (b0 % 4 == 0)
        const int ndw = nrows * 7;
        const int nx4 = ndw >> 2;
        for (int idx = tid; idx < nx4; idx += 256) {
            fvec4 v = __builtin_nontemporal_load(reinterpret_cast<const fvec4*>(src) + idx);
            reinterpret_cast<fvec4*>(sp)[idx] = v;
        }
        for (int idx = (nx4 << 2) + tid; idx < ndw; idx += 256)
            sp[idx] = ntl(src + idx);
    }
    __syncthreads();

    // 3) compute; results into LDS (stride 7 / 6: ≤4-way bank alias, cheap)
    if (active) {
        const float* pr = sp + 7*tid;
        F3 tp = {pr[0], pr[1], pr[2]};
        Q4 qp = {{pr[3], pr[4], pr[5]}, pr[6]};

        float2 a0 = unp2h(r1.x), a1 = unp2h(r1.y), a2 = unp2h(r1.z), a3 = unp2h(r1.w);
        float2 b0f= unp2h(r2.x), b1 = unp2h(r2.y), b2 = unp2h(r2.z), b3 = unp2h(r2.w);
        F3 t1 = {a0.x, a0.y, a1.x};  Q4 q1 = {{a2.x, a2.y, a3.x}, a3.y};
        F3 t2 = {b0f.x, b0f.y, b1.x};  Q4 q2 = {{b2.x, b2.y, b3.x}, b3.y};

        float res[6];
        edge_math(t1, q1, t2, q2, tp, qp, res);
        #pragma unroll
        for (int k = 0; k < 6; ++k) so[6*tid + k] = res[k];
    }
    __syncthreads();

    // 4) coalesced full-line nt stores of the block's 6*nrows outputs
    {
        float* dst = out + 6*(size_t)b0;           // 24*b0 bytes: 16B-aligned
        const int ndw = nrows * 6;
        const int nx4 = ndw >> 2;
        for (int idx = tid; idx < nx4; idx += 256) {
            fvec4 v = reinterpret_cast<const fvec4*>(so)[idx];
            __builtin_nontemporal_store(v, reinterpret_cast<fvec4*>(dst) + idx);
        }
        for (int idx = (nx4 << 2) + tid; idx < ndw; idx += 256)
            nts(dst + idx, so[idx]);
    }
}

// fallback (workspace too small): gather f32 rows directly, 1 edge/thread
__global__ __launch_bounds__(256)
void edge_kernel_direct(const int*   __restrict__ edges,
                        const float* __restrict__ nodes,
                        const float* __restrict__ poses,
                        float*       __restrict__ out,
                        int E)
{
    const int e = blockIdx.x * 256 + threadIdx.x;
    if (e >= E) return;

    ivec2 ij = __builtin_nontemporal_load(reinterpret_cast<const ivec2*>(edges) + e);
    const float* n1 = nodes + 7*(size_t)ij.x;
    const float* n2 = nodes + 7*(size_t)ij.y;
    const float* p  = poses + 7*(size_t)e;

    F3 t1 = {n1[0], n1[1], n1[2]};  Q4 q1 = {{n1[3], n1[4], n1[5]}, n1[6]};
    F3 t2 = {n2[0], n2[1], n2[2]};  Q4 q2 = {{n2[3], n2[4], n2[5]}, n2[6]};

    float res[6];
    edge_math(t1, q1, t2, q2,
              F3{ntl(p+0), ntl(p+1), ntl(p+2)}, Q4{{ntl(p+3), ntl(p+4), ntl(p+5)}, ntl(p+6)},
              res);
    float* o = out + 6*(size_t)e;
    #pragma unroll
    for (int k = 0; k < 6; ++k) nts(o + k, res[k]);
}

extern "C" void kernel_launch(void* const* d_in, const int* in_sizes, int n_in,
                              void* d_out, int out_size, void* d_ws, size_t ws_size,
                              hipStream_t stream) {
    const int*   edges      = (const int*)  d_in[0];
    const float* nodes      = (const float*)d_in[1];
    const float* vels       = (const float*)d_in[2];
    const float* poses      = (const float*)d_in[3];
    const float* imu_drots  = (const float*)d_in[4];
    const float* imu_dtrans = (const float*)d_in[5];
    const float* imu_dvels  = (const float*)d_in[6];
    const float* dts        = (const float*)d_in[7];
    float* out = (float*)d_out;

    const int E = in_sizes[0] / 2;
    const int N = in_sizes[1] / 7;
    const int M = in_sizes[7];

    const size_t off_adjvel   = 6*(size_t)E;
    const size_t off_imurot   = off_adjvel + 3*(size_t)M;
    const size_t off_transvel = off_imurot + 3*(size_t)M;

    const int BLK = 256;
    const int NBLKS = (N + BLK - 1) / BLK;
    const int EBLKS = (E + BLK - 1) / BLK;

    uvec4* nodes16 = (uvec4*)d_ws;
    const bool can_pack = (d_ws != nullptr) && (ws_size >= (size_t)N * 16);

    if (can_pack) {
        prep_kernel<true><<<NBLKS, BLK, 0, stream>>>(nodes, vels, imu_drots, imu_dtrans,
                                                     imu_dvels, dts, out, nodes16, N, M,
                                                     off_adjvel, off_imurot, off_transvel);
        edge_kernel3<<<EBLKS, BLK, 0, stream>>>(edges, nodes16, poses, out, E);
    } else {
        prep_kernel<false><<<NBLKS, BLK, 0, stream>>>(nodes, vels, imu_drots, imu_dtrans,
                                                      imu_dvels, dts, out, nullptr, N, M,
                                                      off_adjvel, off_imurot, off_transvel);
        edge_kernel_direct<<<EBLKS, BLK, 0, stream>>>(edges, nodes, poses, out, E);
    }
}